// Round 2
// baseline (1384.619 us; speedup 1.0000x reference)
//
#include <hip/hip_runtime.h>
#include <stdint.h>

#define N_NODES   100000
#define N_EDGES   3200000
#define N_FEAT    512
#define HIDDEN    64
#define N_CLASSES 40

// ---------------- threefry2x32 (exact JAX semantics, key = (0,42)) ----------
__device__ __forceinline__ uint32_t rotl32(uint32_t x, uint32_t r) {
  return (x << r) | (x >> (32u - r));
}

__device__ __forceinline__ void threefry2x32(uint32_t k0, uint32_t k1,
                                             uint32_t x0, uint32_t x1,
                                             uint32_t& o0, uint32_t& o1) {
  uint32_t ks2 = k0 ^ k1 ^ 0x1BD11BDAu;
  x0 += k0; x1 += k1;
#define TF_R4(a,b,c,d) \
  x0 += x1; x1 = rotl32(x1,a); x1 ^= x0; \
  x0 += x1; x1 = rotl32(x1,b); x1 ^= x0; \
  x0 += x1; x1 = rotl32(x1,c); x1 ^= x0; \
  x0 += x1; x1 = rotl32(x1,d); x1 ^= x0;
  TF_R4(13,15,26,6)   x0 += k1;  x1 += ks2 + 1u;
  TF_R4(17,29,16,24)  x0 += ks2; x1 += k0  + 2u;
  TF_R4(13,15,26,6)   x0 += k0;  x1 += k1  + 3u;
  TF_R4(17,29,16,24)  x0 += k1;  x1 += ks2 + 4u;
  TF_R4(13,15,26,6)   x0 += ks2; x1 += k0  + 5u;
#undef TF_R4
  o0 = x0; o1 = x1;
}

// ---------------- CSR build --------------------------------------------------
__global__ void count_kernel(const int* __restrict__ edges, int* __restrict__ cnt) {
  int e = blockIdx.x * blockDim.x + threadIdx.x;
  if (e < N_EDGES) atomicAdd(&cnt[edges[N_EDGES + e]], 1);
}

__global__ void dinv_kernel(const int* __restrict__ cnt, float* __restrict__ dinv) {
  int n = blockIdx.x * blockDim.x + threadIdx.x;
  if (n < N_NODES) dinv[n] = rsqrtf((float)(cnt[n] + 1));  // +1 self-loop
}

__global__ void scan_a(const int* __restrict__ cnt, int* __restrict__ rowstart,
                       int* __restrict__ bsums) {
  __shared__ int s[1024];
  int t = threadIdx.x, i = blockIdx.x * 1024 + t;
  int v = (i < N_NODES) ? cnt[i] : 0;
  s[t] = v; __syncthreads();
  for (int off = 1; off < 1024; off <<= 1) {
    int a = (t >= off) ? s[t - off] : 0;
    __syncthreads();
    s[t] += a;
    __syncthreads();
  }
  if (i < N_NODES) rowstart[i] = s[t] - v;       // block-local exclusive
  if (t == 1023) bsums[blockIdx.x] = s[t];       // block total
}

__global__ void scan_b(int* __restrict__ bsums, int nb) {
  __shared__ int s[128];
  int t = threadIdx.x;
  int v = (t < nb) ? bsums[t] : 0;
  s[t] = v; __syncthreads();
  for (int off = 1; off < 128; off <<= 1) {
    int a = (t >= off) ? s[t - off] : 0;
    __syncthreads();
    s[t] += a;
    __syncthreads();
  }
  if (t < nb) bsums[t] = s[t] - v;               // exclusive block offsets
}

__global__ void scan_c(int* __restrict__ rowstart, int* __restrict__ cursor,
                       const int* __restrict__ bsums) {
  int t = threadIdx.x, i = blockIdx.x * 1024 + t;
  if (i < N_NODES) {
    int r = rowstart[i] + bsums[blockIdx.x];
    rowstart[i] = r;
    cursor[i] = r;
  }
  if (blockIdx.x == 0 && t == 0) rowstart[N_NODES] = N_EDGES;
}

__global__ void fill_kernel(const int* __restrict__ edges, int* __restrict__ cursor,
                            int* __restrict__ srcs) {
  int e = blockIdx.x * blockDim.x + threadIdx.x;
  if (e < N_EDGES) {
    int s = edges[e];
    int d = edges[N_EDGES + e];
    int pos = atomicAdd(&cursor[d], 1);
    srcs[pos] = s;
  }
}

// ---------------- GEMM1: hs1 = (x @ W1) * dinv[n]   [100000x512 @ 512x64] ----
// 64 nodes x 64 cols per block, KC=32, 4x4 microtile, fp32 VALU.
#define XP 68  // padded LDS leading dim (multiple of 4 for b128, breaks 32-stride)
__global__ __launch_bounds__(256) void gemm1_kernel(const float* __restrict__ x,
                                                    const float* __restrict__ W1,
                                                    const float* __restrict__ dinv,
                                                    float* __restrict__ hs1) {
  __shared__ float Xs[32 * XP];  // [k][node], transposed
  __shared__ float Ws[32 * XP];  // [k][col]
  int t = threadIdx.x;
  int node0 = blockIdx.x * 64;
  int tx = t & 15, ty = t >> 4;  // cols 4tx.., rows 4ty..
  float acc[4][4];
#pragma unroll
  for (int i = 0; i < 4; i++)
#pragma unroll
    for (int j = 0; j < 4; j++) acc[i][j] = 0.f;

  for (int kc = 0; kc < N_FEAT; kc += 32) {
#pragma unroll
    for (int L = 0; L < 2; L++) {           // stage X tile (transpose to [k][node])
      int f = t + L * 256;
      int kq = f & 7, row = f >> 3;         // row 0..63, kq*4 = k offset
      int gr = node0 + row; if (gr > N_NODES - 1) gr = N_NODES - 1;
      const float4 v = *reinterpret_cast<const float4*>(
          &x[(size_t)gr * N_FEAT + kc + kq * 4]);
      Xs[(kq * 4 + 0) * XP + row] = v.x;
      Xs[(kq * 4 + 1) * XP + row] = v.y;
      Xs[(kq * 4 + 2) * XP + row] = v.z;
      Xs[(kq * 4 + 3) * XP + row] = v.w;
    }
#pragma unroll
    for (int L = 0; L < 2; L++) {           // stage W tile (already [k][col])
      int f = t + L * 256;
      int colq = f & 15, kl = f >> 4;
      const float4 v = *reinterpret_cast<const float4*>(
          &W1[(size_t)(kc + kl) * HIDDEN + colq * 4]);
      *reinterpret_cast<float4*>(&Ws[kl * XP + colq * 4]) = v;
    }
    __syncthreads();
#pragma unroll 8
    for (int kl = 0; kl < 32; kl++) {
      const float4 a = *reinterpret_cast<const float4*>(&Xs[kl * XP + ty * 4]);
      const float4 b = *reinterpret_cast<const float4*>(&Ws[kl * XP + tx * 4]);
      float ar[4] = {a.x, a.y, a.z, a.w};
      float br[4] = {b.x, b.y, b.z, b.w};
#pragma unroll
      for (int i = 0; i < 4; i++)
#pragma unroll
        for (int j = 0; j < 4; j++) acc[i][j] += ar[i] * br[j];
    }
    __syncthreads();
  }
#pragma unroll
  for (int i = 0; i < 4; i++) {
    int node = node0 + ty * 4 + i;
    if (node < N_NODES) {
      float dv = dinv[node];
      float4 o;
      o.x = acc[i][0] * dv; o.y = acc[i][1] * dv;
      o.z = acc[i][2] * dv; o.w = acc[i][3] * dv;
      *reinterpret_cast<float4*>(&hs1[(size_t)node * HIDDEN + tx * 4]) = o;
    }
  }
}

// ---------------- GEMM2: gs = (h1 @ W2) * dinv[n]   [100000x64 @ 64x40] ------
__global__ __launch_bounds__(256) void gemm2_kernel(const float* __restrict__ h1,
                                                    const float* __restrict__ W2,
                                                    const float* __restrict__ dinv,
                                                    float* __restrict__ gs) {
  __shared__ float w2s[HIDDEN * N_CLASSES + 64];  // pad: lanes >=40 read junk safely
  int t = threadIdx.x;
  for (int i = t; i < HIDDEN * N_CLASSES; i += 256) w2s[i] = W2[i];
  __syncthreads();
  int wid = (blockIdx.x * 256 + t) >> 6;
  int lane = t & 63;
  if (wid >= N_NODES) return;
  float hv = h1[(size_t)wid * HIDDEN + lane];  // lane j holds h[n][j]
  float acc = 0.f;
#pragma unroll 8
  for (int j = 0; j < HIDDEN; j++) {
    float hj = __shfl(hv, j);
    acc += hj * w2s[j * N_CLASSES + lane];     // lanes >=40 compute junk, never stored
  }
  if (lane < N_CLASSES) gs[(size_t)wid * N_CLASSES + lane] = acc * dinv[wid];
}

// ---------------- Pull aggregation: out[d] = dinv[d]*(hs[d]+sum hs[src]) + b -
template <int F, bool RELU_DROP>
__global__ __launch_bounds__(256) void agg_kernel(const float* __restrict__ hs,
                                                  const int* __restrict__ rowstart,
                                                  const int* __restrict__ srcs,
                                                  const float* __restrict__ dinv,
                                                  const float* __restrict__ bias,
                                                  float* __restrict__ outp) {
  int wid = (blockIdx.x * 256 + threadIdx.x) >> 6;  // one wave per dst node
  int lane = threadIdx.x & 63;
  if (wid >= N_NODES) return;
  int beg = rowstart[wid], end = rowstart[wid + 1];
  float acc = 0.f;
  if (lane < F) acc = hs[(size_t)wid * F + lane];   // self-loop term
  for (int e = beg; e < end; ++e) {
    int s = srcs[e];
    if (lane < F) acc += hs[(size_t)s * F + lane];
  }
  if (lane < F) {
    float v = acc * dinv[wid] + bias[lane];
    if (RELU_DROP) {
      v = fmaxf(v, 0.f);
      // JAX dropout, jax_threefry_partitionable=True (modern default):
      // element i draws threefry2x32(key=(0,42), counter=(hi32(i), lo32(i))),
      // 32-bit draw = o0 ^ o1; uniform<0.5 <=> top bit clear; scale kept by 2x.
      uint32_t i = (uint32_t)wid * 64u + (uint32_t)lane;
      uint32_t o0, o1;
      threefry2x32(0u, 42u, 0u, i, o0, o1);
      uint32_t bits = o0 ^ o1;
      v = (bits & 0x80000000u) ? 0.f : v * 2.f;
    }
    outp[(size_t)wid * F + lane] = v;
  }
}

// ---------------- launch -----------------------------------------------------
extern "C" void kernel_launch(void* const* d_in, const int* in_sizes, int n_in,
                              void* d_out, int out_size, void* d_ws, size_t ws_size,
                              hipStream_t stream) {
  const float* x   = (const float*)d_in[0];
  const int* edges = (const int*)d_in[1];  // [2*E] int32: row0=src, row1=dst
  const float* W1  = (const float*)d_in[2];
  const float* b1  = (const float*)d_in[3];
  const float* W2  = (const float*)d_in[4];
  const float* b2  = (const float*)d_in[5];
  float* out = (float*)d_out;

  char* ws = (char*)d_ws;
  size_t off = 0;
  auto alloc = [&](size_t bytes) -> void* {
    void* p = ws + off;
    off = (off + bytes + 255) & ~(size_t)255;
    return p;
  };
  int*   cnt      = (int*)alloc((size_t)N_NODES * 4);
  int*   rowstart = (int*)alloc((size_t)(N_NODES + 1) * 4);
  int*   cursor   = (int*)alloc((size_t)N_NODES * 4);
  float* dinv     = (float*)alloc((size_t)N_NODES * 4);
  int*   bsums    = (int*)alloc(128 * 4);
  int*   srcs     = (int*)alloc((size_t)N_EDGES * 4);
  float* hs1      = (float*)alloc((size_t)N_NODES * HIDDEN * 4);
  float* h1       = (float*)alloc((size_t)N_NODES * HIDDEN * 4);
  float* gs       = hs1;  // hs1 dead after agg1; reuse for layer-2 transform

  hipMemsetAsync(cnt, 0, (size_t)N_NODES * 4, stream);
  count_kernel<<<(N_EDGES + 255) / 256, 256, 0, stream>>>(edges, cnt);
  dinv_kernel<<<(N_NODES + 255) / 256, 256, 0, stream>>>(cnt, dinv);
  int nb = (N_NODES + 1023) / 1024;  // 98
  scan_a<<<nb, 1024, 0, stream>>>(cnt, rowstart, bsums);
  scan_b<<<1, 128, 0, stream>>>(bsums, nb);
  scan_c<<<nb, 1024, 0, stream>>>(rowstart, cursor, bsums);
  fill_kernel<<<(N_EDGES + 255) / 256, 256, 0, stream>>>(edges, cursor, srcs);
  gemm1_kernel<<<(N_NODES + 63) / 64, 256, 0, stream>>>(x, W1, dinv, hs1);
  agg_kernel<HIDDEN, true><<<(N_NODES * 64 + 255) / 256, 256, 0, stream>>>(
      hs1, rowstart, srcs, dinv, b1, h1);
  gemm2_kernel<<<(N_NODES * 64 + 255) / 256, 256, 0, stream>>>(h1, W2, dinv, gs);
  agg_kernel<N_CLASSES, false><<<(N_NODES * 64 + 255) / 256, 256, 0, stream>>>(
      gs, rowstart, srcs, dinv, b2, out);
}

// Round 3
// 928.703 us; speedup vs baseline: 1.4909x; 1.4909x over previous
//
#include <hip/hip_runtime.h>
#include <stdint.h>

#define N_NODES   100000
#define N_EDGES   3200000
#define N_FEAT    512
#define HIDDEN    64
#define N_CLASSES 40

#define NB    98      // coarse buckets = ceil(N_NODES/1024), ties to scan_c blocks
#define BSH   10      // bucket = dst >> 10
#define CHUNK 4096    // edges per bin_kernel workgroup

// ---------------- threefry2x32 (exact JAX semantics, key = (0,42)) ----------
__device__ __forceinline__ uint32_t rotl32(uint32_t x, uint32_t r) {
  return (x << r) | (x >> (32u - r));
}

__device__ __forceinline__ void threefry2x32(uint32_t k0, uint32_t k1,
                                             uint32_t x0, uint32_t x1,
                                             uint32_t& o0, uint32_t& o1) {
  uint32_t ks2 = k0 ^ k1 ^ 0x1BD11BDAu;
  x0 += k0; x1 += k1;
#define TF_R4(a,b,c,d) \
  x0 += x1; x1 = rotl32(x1,a); x1 ^= x0; \
  x0 += x1; x1 = rotl32(x1,b); x1 ^= x0; \
  x0 += x1; x1 = rotl32(x1,c); x1 ^= x0; \
  x0 += x1; x1 = rotl32(x1,d); x1 ^= x0;
  TF_R4(13,15,26,6)   x0 += k1;  x1 += ks2 + 1u;
  TF_R4(17,29,16,24)  x0 += ks2; x1 += k0  + 2u;
  TF_R4(13,15,26,6)   x0 += k0;  x1 += k1  + 3u;
  TF_R4(17,29,16,24)  x0 += k1;  x1 += ks2 + 4u;
  TF_R4(13,15,26,6)   x0 += ks2; x1 += k0  + 5u;
#undef TF_R4
  o0 = x0; o1 = x1;
}

// ---------------- degree count + scan ---------------------------------------
__global__ void count_kernel(const int* __restrict__ edges, int* __restrict__ cnt) {
  int e = blockIdx.x * blockDim.x + threadIdx.x;
  if (e < N_EDGES) atomicAdd(&cnt[edges[N_EDGES + e]], 1);
}

__global__ void dinv_kernel(const int* __restrict__ cnt, float* __restrict__ dinv) {
  int n = blockIdx.x * blockDim.x + threadIdx.x;
  if (n < N_NODES) dinv[n] = rsqrtf((float)(cnt[n] + 1));  // +1 self-loop
}

__global__ void scan_a(const int* __restrict__ cnt, int* __restrict__ rowstart,
                       int* __restrict__ bsums) {
  __shared__ int s[1024];
  int t = threadIdx.x, i = blockIdx.x * 1024 + t;
  int v = (i < N_NODES) ? cnt[i] : 0;
  s[t] = v; __syncthreads();
  for (int off = 1; off < 1024; off <<= 1) {
    int a = (t >= off) ? s[t - off] : 0;
    __syncthreads();
    s[t] += a;
    __syncthreads();
  }
  if (i < N_NODES) rowstart[i] = s[t] - v;       // block-local exclusive
  if (t == 1023) bsums[blockIdx.x] = s[t];       // block total
}

__global__ void scan_b(int* __restrict__ bsums, int nb) {
  __shared__ int s[128];
  int t = threadIdx.x;
  int v = (t < nb) ? bsums[t] : 0;
  s[t] = v; __syncthreads();
  for (int off = 1; off < 128; off <<= 1) {
    int a = (t >= off) ? s[t - off] : 0;
    __syncthreads();
    s[t] += a;
    __syncthreads();
  }
  if (t < nb) bsums[t] = s[t] - v;               // exclusive block offsets
}

__global__ void scan_c(int* __restrict__ rowstart, int* __restrict__ cursor,
                       const int* __restrict__ bsums, int* __restrict__ gcursor) {
  int t = threadIdx.x, i = blockIdx.x * 1024 + t;
  if (i < N_NODES) {
    int r = rowstart[i] + bsums[blockIdx.x];
    rowstart[i] = r;
    cursor[i] = r;
    if (t == 0) gcursor[blockIdx.x] = r;  // bucket append cursor = region start
  }
  if (blockIdx.x == 0 && t == 0) rowstart[N_NODES] = N_EDGES;
}

// ---------------- level 1: LDS counting-sort into coarse buckets -------------
// Chunks of 4096 edges sorted by dst>>10 in LDS, then bucket-contiguous runs
// (avg ~42 pairs = 336 B) appended to exact per-bucket regions of gbins.
// Kills the 15x write amplification of the naive 4 B random scatter.
__global__ __launch_bounds__(256) void bin_kernel(const int* __restrict__ edges,
                                                  int* __restrict__ gcursor,
                                                  int2* __restrict__ gbins) {
  __shared__ int bcnt[128];
  __shared__ int sc[128];
  __shared__ int bs[NB + 1];
  __shared__ int gbase[NB];
  __shared__ int2 sorted[CHUNK];

  int t = threadIdx.x;
  int base = blockIdx.x * CHUNK;
  int s[16], d[16], pos[16];
#pragma unroll
  for (int i = 0; i < 16; i++) {
    int e = base + i * 256 + t;
    if (e < N_EDGES) { s[i] = edges[e]; d[i] = edges[N_EDGES + e]; }
    else d[i] = -1;
  }
  if (t < 128) bcnt[t] = 0;
  __syncthreads();
#pragma unroll
  for (int i = 0; i < 16; i++)
    if (d[i] >= 0) pos[i] = atomicAdd(&bcnt[d[i] >> BSH], 1);
  __syncthreads();
  if (t < 128) sc[t] = bcnt[t];
  __syncthreads();
  for (int off = 1; off < 128; off <<= 1) {       // Hillis-Steele inclusive scan
    int v = (t < 128 && t >= off) ? sc[t - off] : 0;
    __syncthreads();
    if (t < 128) sc[t] += v;
    __syncthreads();
  }
  if (t < NB) bs[t] = sc[t] - bcnt[t];            // exclusive starts
  if (t == 0) bs[NB] = sc[NB - 1];
  if (t < NB && bcnt[t] > 0) gbase[t] = atomicAdd(&gcursor[t], bcnt[t]);
  __syncthreads();
#pragma unroll
  for (int i = 0; i < 16; i++)
    if (d[i] >= 0) sorted[bs[d[i] >> BSH] + pos[i]] = make_int2(s[i], d[i]);
  __syncthreads();
  int total = bs[NB];
  for (int p = t; p < total; p += 256) {
    int lo = 0, hi = NB - 1;                      // find bucket: bs[b] <= p < bs[b+1]
    while (lo < hi) { int mid = (lo + hi + 1) >> 1; if (bs[mid] <= p) lo = mid; else hi = mid - 1; }
    gbins[gbase[lo] + (p - bs[lo])] = sorted[p];
  }
}

// ---------------- level 2: fine scatter within L2-resident bucket window -----
__global__ __launch_bounds__(1024) void fine_kernel(const int2* __restrict__ gbins,
                                                    const int* __restrict__ rowstart,
                                                    int* __restrict__ cursor,
                                                    int* __restrict__ srcs) {
  int b = blockIdx.x;
  int nend = (b + 1) << BSH; if (nend > N_NODES) nend = N_NODES;
  int lo = rowstart[b << BSH], hi = rowstart[nend];
  int len = hi - lo;
  int st = lo + (len * blockIdx.y) / 2;
  int en = lo + (len * (blockIdx.y + 1)) / 2;
  for (int p = st + (int)threadIdx.x; p < en; p += 1024) {
    int2 pr = gbins[p];
    int pos = atomicAdd(&cursor[pr.y], 1);
    srcs[pos] = pr.x;   // confined to ~131 KB window => full lines, no amplification
  }
}

// ---------------- GEMM1: hs1 = (x @ W1) * dinv[n]   [100000x512 @ 512x64] ----
#define XP 68  // padded LDS leading dim
__global__ __launch_bounds__(256) void gemm1_kernel(const float* __restrict__ x,
                                                    const float* __restrict__ W1,
                                                    const float* __restrict__ dinv,
                                                    float* __restrict__ hs1) {
  __shared__ float Xs[32 * XP];  // [k][node], transposed
  __shared__ float Ws[32 * XP];  // [k][col]
  int t = threadIdx.x;
  int node0 = blockIdx.x * 64;
  int tx = t & 15, ty = t >> 4;
  float acc[4][4];
#pragma unroll
  for (int i = 0; i < 4; i++)
#pragma unroll
    for (int j = 0; j < 4; j++) acc[i][j] = 0.f;

  for (int kc = 0; kc < N_FEAT; kc += 32) {
#pragma unroll
    for (int L = 0; L < 2; L++) {
      int f = t + L * 256;
      int kq = f & 7, row = f >> 3;
      int gr = node0 + row; if (gr > N_NODES - 1) gr = N_NODES - 1;
      const float4 v = *reinterpret_cast<const float4*>(
          &x[(size_t)gr * N_FEAT + kc + kq * 4]);
      Xs[(kq * 4 + 0) * XP + row] = v.x;
      Xs[(kq * 4 + 1) * XP + row] = v.y;
      Xs[(kq * 4 + 2) * XP + row] = v.z;
      Xs[(kq * 4 + 3) * XP + row] = v.w;
    }
#pragma unroll
    for (int L = 0; L < 2; L++) {
      int f = t + L * 256;
      int colq = f & 15, kl = f >> 4;
      const float4 v = *reinterpret_cast<const float4*>(
          &W1[(size_t)(kc + kl) * HIDDEN + colq * 4]);
      *reinterpret_cast<float4*>(&Ws[kl * XP + colq * 4]) = v;
    }
    __syncthreads();
#pragma unroll 8
    for (int kl = 0; kl < 32; kl++) {
      const float4 a = *reinterpret_cast<const float4*>(&Xs[kl * XP + ty * 4]);
      const float4 b = *reinterpret_cast<const float4*>(&Ws[kl * XP + tx * 4]);
      float ar[4] = {a.x, a.y, a.z, a.w};
      float br[4] = {b.x, b.y, b.z, b.w};
#pragma unroll
      for (int i = 0; i < 4; i++)
#pragma unroll
        for (int j = 0; j < 4; j++) acc[i][j] += ar[i] * br[j];
    }
    __syncthreads();
  }
#pragma unroll
  for (int i = 0; i < 4; i++) {
    int node = node0 + ty * 4 + i;
    if (node < N_NODES) {
      float dv = dinv[node];
      float4 o;
      o.x = acc[i][0] * dv; o.y = acc[i][1] * dv;
      o.z = acc[i][2] * dv; o.w = acc[i][3] * dv;
      *reinterpret_cast<float4*>(&hs1[(size_t)node * HIDDEN + tx * 4]) = o;
    }
  }
}

// ---------------- GEMM2: gs = (h1 @ W2) * dinv[n]   [100000x64 @ 64x40] ------
__global__ __launch_bounds__(256) void gemm2_kernel(const float* __restrict__ h1,
                                                    const float* __restrict__ W2,
                                                    const float* __restrict__ dinv,
                                                    float* __restrict__ gs) {
  __shared__ float w2s[HIDDEN * N_CLASSES + 64];
  int t = threadIdx.x;
  for (int i = t; i < HIDDEN * N_CLASSES; i += 256) w2s[i] = W2[i];
  __syncthreads();
  int wid = (blockIdx.x * 256 + t) >> 6;
  int lane = t & 63;
  if (wid >= N_NODES) return;
  float hv = h1[(size_t)wid * HIDDEN + lane];
  float acc = 0.f;
#pragma unroll 8
  for (int j = 0; j < HIDDEN; j++) {
    float hj = __shfl(hv, j);
    acc += hj * w2s[j * N_CLASSES + lane];
  }
  if (lane < N_CLASSES) gs[(size_t)wid * N_CLASSES + lane] = acc * dinv[wid];
}

// ---------------- Pull aggregation: out[d] = dinv[d]*(hs[d]+sum hs[src]) + b -
template <int F, bool RELU_DROP>
__global__ __launch_bounds__(256) void agg_kernel(const float* __restrict__ hs,
                                                  const int* __restrict__ rowstart,
                                                  const int* __restrict__ srcs,
                                                  const float* __restrict__ dinv,
                                                  const float* __restrict__ bias,
                                                  float* __restrict__ outp) {
  int wid = (blockIdx.x * 256 + threadIdx.x) >> 6;  // one wave per dst node
  int lane = threadIdx.x & 63;
  if (wid >= N_NODES) return;
  int beg = rowstart[wid], end = rowstart[wid + 1];
  float acc = 0.f;
  if (lane < F) acc = hs[(size_t)wid * F + lane];   // self-loop term
  int e = beg;
  for (; e + 4 <= end; e += 4) {                    // 4 gathers in flight
    int s0 = srcs[e], s1 = srcs[e + 1], s2 = srcs[e + 2], s3 = srcs[e + 3];
    if (lane < F) {
      float a0 = hs[(size_t)s0 * F + lane];
      float a1 = hs[(size_t)s1 * F + lane];
      float a2 = hs[(size_t)s2 * F + lane];
      float a3 = hs[(size_t)s3 * F + lane];
      acc += (a0 + a1) + (a2 + a3);
    }
  }
  for (; e < end; ++e) {
    int s = srcs[e];
    if (lane < F) acc += hs[(size_t)s * F + lane];
  }
  if (lane < F) {
    float v = acc * dinv[wid] + bias[lane];
    if (RELU_DROP) {
      v = fmaxf(v, 0.f);
      // JAX dropout, jax_threefry_partitionable=True:
      // bits(i) = o0^o1 of threefry2x32(key=(0,42), (0,i)); drop iff bit31 set.
      uint32_t i = (uint32_t)wid * 64u + (uint32_t)lane;
      uint32_t o0, o1;
      threefry2x32(0u, 42u, 0u, i, o0, o1);
      uint32_t bits = o0 ^ o1;
      v = (bits & 0x80000000u) ? 0.f : v * 2.f;
    }
    outp[(size_t)wid * F + lane] = v;
  }
}

// ---------------- launch -----------------------------------------------------
extern "C" void kernel_launch(void* const* d_in, const int* in_sizes, int n_in,
                              void* d_out, int out_size, void* d_ws, size_t ws_size,
                              hipStream_t stream) {
  const float* x   = (const float*)d_in[0];
  const int* edges = (const int*)d_in[1];  // [2*E] int32: row0=src, row1=dst
  const float* W1  = (const float*)d_in[2];
  const float* b1  = (const float*)d_in[3];
  const float* W2  = (const float*)d_in[4];
  const float* b2  = (const float*)d_in[5];
  float* out = (float*)d_out;

  char* ws = (char*)d_ws;
  size_t off = 0;
  auto alloc = [&](size_t bytes) -> void* {
    void* p = ws + off;
    off = (off + bytes + 255) & ~(size_t)255;
    return p;
  };
  int*   cnt      = (int*)alloc((size_t)N_NODES * 4);
  int*   rowstart = (int*)alloc((size_t)(N_NODES + 1) * 4);
  int*   cursor   = (int*)alloc((size_t)N_NODES * 4);
  float* dinv     = (float*)alloc((size_t)N_NODES * 4);
  int*   bsums    = (int*)alloc(128 * 4);
  int*   gcursor  = (int*)alloc(128 * 4);
  int*   srcs     = (int*)alloc((size_t)N_EDGES * 4);
  float* hs1      = (float*)alloc((size_t)N_NODES * HIDDEN * 4);
  float* h1       = (float*)alloc((size_t)N_NODES * HIDDEN * 4);
  float* gs       = hs1;            // hs1 dead after agg1; reuse for layer 2
  int2*  gbins    = (int2*)hs1;     // 3.2M*8B == 100000*64*4B; dead before gemm1

  hipMemsetAsync(cnt, 0, (size_t)N_NODES * 4, stream);
  count_kernel<<<(N_EDGES + 255) / 256, 256, 0, stream>>>(edges, cnt);
  dinv_kernel<<<(N_NODES + 255) / 256, 256, 0, stream>>>(cnt, dinv);
  int nb = (N_NODES + 1023) / 1024;  // 98 == NB
  scan_a<<<nb, 1024, 0, stream>>>(cnt, rowstart, bsums);
  scan_b<<<1, 128, 0, stream>>>(bsums, nb);
  scan_c<<<nb, 1024, 0, stream>>>(rowstart, cursor, bsums, gcursor);
  bin_kernel<<<(N_EDGES + CHUNK - 1) / CHUNK, 256, 0, stream>>>(edges, gcursor, gbins);
  fine_kernel<<<dim3(NB, 2), 1024, 0, stream>>>(gbins, rowstart, cursor, srcs);
  gemm1_kernel<<<(N_NODES + 63) / 64, 256, 0, stream>>>(x, W1, dinv, hs1);
  agg_kernel<HIDDEN, true><<<(N_NODES * 64 + 255) / 256, 256, 0, stream>>>(
      hs1, rowstart, srcs, dinv, b1, h1);
  gemm2_kernel<<<(N_NODES * 64 + 255) / 256, 256, 0, stream>>>(h1, W2, dinv, gs);
  agg_kernel<N_CLASSES, false><<<(N_NODES * 64 + 255) / 256, 256, 0, stream>>>(
      gs, rowstart, srcs, dinv, b2, out);
}

// Round 4
// 739.935 us; speedup vs baseline: 1.8713x; 1.2551x over previous
//
#include <hip/hip_runtime.h>
#include <stdint.h>

#define N_NODES   100000
#define N_EDGES   3200000
#define N_FEAT    512
#define HIDDEN    64
#define N_CLASSES 40

#define BSH   9                      // bucket = dst >> 9 (512 nodes per bucket)
#define NB    196                    // ceil(100000/512)
#define CAP   18432                  // bucket region capacity; mean 16384, +16 sigma
#define CHUNK 4096                   // edges per bin_kernel workgroup

// ---------------- threefry2x32 (exact JAX semantics, key = (0,42)) ----------
__device__ __forceinline__ uint32_t rotl32(uint32_t x, uint32_t r) {
  return (x << r) | (x >> (32u - r));
}

__device__ __forceinline__ void threefry2x32(uint32_t k0, uint32_t k1,
                                             uint32_t x0, uint32_t x1,
                                             uint32_t& o0, uint32_t& o1) {
  uint32_t ks2 = k0 ^ k1 ^ 0x1BD11BDAu;
  x0 += k0; x1 += k1;
#define TF_R4(a,b,c,d) \
  x0 += x1; x1 = rotl32(x1,a); x1 ^= x0; \
  x0 += x1; x1 = rotl32(x1,b); x1 ^= x0; \
  x0 += x1; x1 = rotl32(x1,c); x1 ^= x0; \
  x0 += x1; x1 = rotl32(x1,d); x1 ^= x0;
  TF_R4(13,15,26,6)   x0 += k1;  x1 += ks2 + 1u;
  TF_R4(17,29,16,24)  x0 += ks2; x1 += k0  + 2u;
  TF_R4(13,15,26,6)   x0 += k0;  x1 += k1  + 3u;
  TF_R4(17,29,16,24)  x0 += k1;  x1 += ks2 + 4u;
  TF_R4(13,15,26,6)   x0 += ks2; x1 += k0  + 5u;
#undef TF_R4
  o0 = x0; o1 = x1;
}

// ---------------- CSR build (no per-edge global atomics anywhere) ------------
__global__ void init_kernel(int* __restrict__ gcursor) {
  int t = threadIdx.x;
  if (t < NB) gcursor[t] = t * CAP;  // fixed-capacity bucket regions
}

// Level 1: LDS counting-sort of 4096-edge chunks into NB coarse buckets; runs
// appended to per-bucket regions (one global atomic per bucket per chunk).
// Entries packed (src<<9)|(dst&511) -> 4 B, halving gbins traffic vs int2.
__global__ __launch_bounds__(256) void bin_kernel(const int* __restrict__ edges,
                                                  int* __restrict__ gcursor,
                                                  uint32_t* __restrict__ gbins) {
  __shared__ int bcnt[256];
  __shared__ int sc[256];
  __shared__ int bs[NB + 1];
  __shared__ int gbase[NB];
  __shared__ uint32_t sorted[CHUNK];

  int t = threadIdx.x;
  int base = blockIdx.x * CHUNK;
  int s[16], d[16], pos[16];
#pragma unroll
  for (int i = 0; i < 16; i++) {
    int e = base + i * 256 + t;
    if (e < N_EDGES) { s[i] = edges[e]; d[i] = edges[N_EDGES + e]; }
    else d[i] = -1;
  }
  bcnt[t] = 0;
  __syncthreads();
#pragma unroll
  for (int i = 0; i < 16; i++)
    if (d[i] >= 0) pos[i] = atomicAdd(&bcnt[d[i] >> BSH], 1);
  __syncthreads();
  sc[t] = bcnt[t];
  __syncthreads();
  for (int off = 1; off < 256; off <<= 1) {       // Hillis-Steele inclusive scan
    int v = (t >= off) ? sc[t - off] : 0;
    __syncthreads();
    sc[t] += v;
    __syncthreads();
  }
  if (t < NB) bs[t] = sc[t] - bcnt[t];            // exclusive starts
  if (t == 255) bs[NB] = sc[255];
  if (t < NB && bcnt[t] > 0) gbase[t] = atomicAdd(&gcursor[t], bcnt[t]);
  __syncthreads();
#pragma unroll
  for (int i = 0; i < 16; i++)
    if (d[i] >= 0)
      sorted[bs[d[i] >> BSH] + pos[i]] =
          ((uint32_t)s[i] << BSH) | ((uint32_t)d[i] & ((1u << BSH) - 1));
  __syncthreads();
  int total = bs[NB];
  for (int p = t; p < total; p += 256) {
    int lo = 0, hi = NB - 1;                      // bucket: bs[b] <= p < bs[b+1]
    while (lo < hi) { int mid = (lo + hi + 1) >> 1; if (bs[mid] <= p) lo = mid; else hi = mid - 1; }
    gbins[gbase[lo] + (p - bs[lo])] = sorted[p];
  }
}

// Exclusive scan of the NB bucket sizes -> bucket start offsets in srcs.
__global__ void sizes_scan(const int* __restrict__ gcursor, int* __restrict__ bstart,
                           int* __restrict__ rowstart) {
  __shared__ int s[256];
  int t = threadIdx.x;
  int v = (t < NB) ? (gcursor[t] - t * CAP) : 0;
  s[t] = v; __syncthreads();
  for (int off = 1; off < 256; off <<= 1) {
    int a = (t >= off) ? s[t - off] : 0;
    __syncthreads();
    s[t] += a;
    __syncthreads();
  }
  if (t < NB) bstart[t] = s[t] - v;
  if (t == 255) bstart[NB] = s[255];              // == N_EDGES
  if (t == 0) rowstart[N_NODES] = N_EDGES;
}

// Level 2: one block per bucket. Per-node degree via LDS atomics, LDS scan ->
// rowstart/dinv, then fine scatter of srcs through LDS cursors. The bucket's
// ~65 KB gbins region is read twice (L2-hot). Zero per-edge global atomics.
__global__ __launch_bounds__(512) void node_kernel(const uint32_t* __restrict__ gbins,
                                                   const int* __restrict__ bstart,
                                                   int* __restrict__ rowstart,
                                                   int* __restrict__ srcs,
                                                   float* __restrict__ dinv) {
  __shared__ int deg[512];
  __shared__ int loc[512];
  __shared__ int cur[512];
  int b = blockIdx.x, t = threadIdx.x;
  int rbase = b * CAP;
  int obase = bstart[b];
  int sz = bstart[b + 1] - obase;
  deg[t] = 0;
  __syncthreads();
  for (int p = t; p < sz; p += 512)
    atomicAdd(&deg[gbins[rbase + p] & ((1u << BSH) - 1)], 1);
  __syncthreads();
  int v = deg[t];
  loc[t] = v;
  __syncthreads();
  for (int off = 1; off < 512; off <<= 1) {       // inclusive scan
    int a = (t >= off) ? loc[t - off] : 0;
    __syncthreads();
    loc[t] += a;
    __syncthreads();
  }
  int excl = loc[t] - v;
  cur[t] = excl;
  int node = (b << BSH) + t;
  if (node < N_NODES) {
    rowstart[node] = obase + excl;
    dinv[node] = rsqrtf((float)(v + 1));          // +1 self-loop
  }
  __syncthreads();
  for (int p = t; p < sz; p += 512) {
    uint32_t e = gbins[rbase + p];
    int pos = atomicAdd(&cur[e & ((1u << BSH) - 1)], 1);
    srcs[obase + pos] = (int)(e >> BSH);
  }
}

// ---------------- GEMM1: hs1 = (x @ W1) * dinv[n]   [100000x512 @ 512x64] ----
#define XP 68  // padded LDS leading dim
__global__ __launch_bounds__(256) void gemm1_kernel(const float* __restrict__ x,
                                                    const float* __restrict__ W1,
                                                    const float* __restrict__ dinv,
                                                    float* __restrict__ hs1) {
  __shared__ float Xs[32 * XP];  // [k][node], transposed
  __shared__ float Ws[32 * XP];  // [k][col]
  int t = threadIdx.x;
  int node0 = blockIdx.x * 64;
  int tx = t & 15, ty = t >> 4;
  float acc[4][4];
#pragma unroll
  for (int i = 0; i < 4; i++)
#pragma unroll
    for (int j = 0; j < 4; j++) acc[i][j] = 0.f;

  for (int kc = 0; kc < N_FEAT; kc += 32) {
#pragma unroll
    for (int L = 0; L < 2; L++) {
      int f = t + L * 256;
      int kq = f & 7, row = f >> 3;
      int gr = node0 + row; if (gr > N_NODES - 1) gr = N_NODES - 1;
      const float4 v = *reinterpret_cast<const float4*>(
          &x[(size_t)gr * N_FEAT + kc + kq * 4]);
      Xs[(kq * 4 + 0) * XP + row] = v.x;
      Xs[(kq * 4 + 1) * XP + row] = v.y;
      Xs[(kq * 4 + 2) * XP + row] = v.z;
      Xs[(kq * 4 + 3) * XP + row] = v.w;
    }
#pragma unroll
    for (int L = 0; L < 2; L++) {
      int f = t + L * 256;
      int colq = f & 15, kl = f >> 4;
      const float4 v = *reinterpret_cast<const float4*>(
          &W1[(size_t)(kc + kl) * HIDDEN + colq * 4]);
      *reinterpret_cast<float4*>(&Ws[kl * XP + colq * 4]) = v;
    }
    __syncthreads();
#pragma unroll 8
    for (int kl = 0; kl < 32; kl++) {
      const float4 a = *reinterpret_cast<const float4*>(&Xs[kl * XP + ty * 4]);
      const float4 b = *reinterpret_cast<const float4*>(&Ws[kl * XP + tx * 4]);
      float ar[4] = {a.x, a.y, a.z, a.w};
      float br[4] = {b.x, b.y, b.z, b.w};
#pragma unroll
      for (int i = 0; i < 4; i++)
#pragma unroll
        for (int j = 0; j < 4; j++) acc[i][j] += ar[i] * br[j];
    }
    __syncthreads();
  }
#pragma unroll
  for (int i = 0; i < 4; i++) {
    int node = node0 + ty * 4 + i;
    if (node < N_NODES) {
      float dv = dinv[node];
      float4 o;
      o.x = acc[i][0] * dv; o.y = acc[i][1] * dv;
      o.z = acc[i][2] * dv; o.w = acc[i][3] * dv;
      *reinterpret_cast<float4*>(&hs1[(size_t)node * HIDDEN + tx * 4]) = o;
    }
  }
}

// ---------------- GEMM2: gs = (h1 @ W2) * dinv[n]   [100000x64 @ 64x40] ------
__global__ __launch_bounds__(256) void gemm2_kernel(const float* __restrict__ h1,
                                                    const float* __restrict__ W2,
                                                    const float* __restrict__ dinv,
                                                    float* __restrict__ gs) {
  __shared__ float w2s[HIDDEN * N_CLASSES + 64];
  int t = threadIdx.x;
  for (int i = t; i < HIDDEN * N_CLASSES; i += 256) w2s[i] = W2[i];
  __syncthreads();
  int wid = (blockIdx.x * 256 + t) >> 6;
  int lane = t & 63;
  if (wid >= N_NODES) return;
  float hv = h1[(size_t)wid * HIDDEN + lane];
  float acc = 0.f;
#pragma unroll 8
  for (int j = 0; j < HIDDEN; j++) {
    float hj = __shfl(hv, j);
    acc += hj * w2s[j * N_CLASSES + lane];
  }
  if (lane < N_CLASSES) gs[(size_t)wid * N_CLASSES + lane] = acc * dinv[wid];
}

// ---------------- Pull aggregation: out[d] = dinv[d]*(hs[d]+sum hs[src]) + b -
template <int F, bool RELU_DROP>
__global__ __launch_bounds__(256) void agg_kernel(const float* __restrict__ hs,
                                                  const int* __restrict__ rowstart,
                                                  const int* __restrict__ srcs,
                                                  const float* __restrict__ dinv,
                                                  const float* __restrict__ bias,
                                                  float* __restrict__ outp) {
  int wid = (blockIdx.x * 256 + threadIdx.x) >> 6;  // one wave per dst node
  int lane = threadIdx.x & 63;
  if (wid >= N_NODES) return;
  int beg = rowstart[wid], end = rowstart[wid + 1];
  float acc = 0.f;
  if (lane < F) acc = hs[(size_t)wid * F + lane];   // self-loop term
  int e = beg;
  for (; e + 4 <= end; e += 4) {                    // 4 gathers in flight
    int s0 = srcs[e], s1 = srcs[e + 1], s2 = srcs[e + 2], s3 = srcs[e + 3];
    if (lane < F) {
      float a0 = hs[(size_t)s0 * F + lane];
      float a1 = hs[(size_t)s1 * F + lane];
      float a2 = hs[(size_t)s2 * F + lane];
      float a3 = hs[(size_t)s3 * F + lane];
      acc += (a0 + a1) + (a2 + a3);
    }
  }
  for (; e < end; ++e) {
    int s = srcs[e];
    if (lane < F) acc += hs[(size_t)s * F + lane];
  }
  if (lane < F) {
    float v = acc * dinv[wid] + bias[lane];
    if (RELU_DROP) {
      v = fmaxf(v, 0.f);
      // JAX dropout, jax_threefry_partitionable=True:
      // bits(i) = o0^o1 of threefry2x32(key=(0,42), (0,i)); drop iff bit31 set.
      uint32_t i = (uint32_t)wid * 64u + (uint32_t)lane;
      uint32_t o0, o1;
      threefry2x32(0u, 42u, 0u, i, o0, o1);
      uint32_t bits = o0 ^ o1;
      v = (bits & 0x80000000u) ? 0.f : v * 2.f;
    }
    outp[(size_t)wid * F + lane] = v;
  }
}

// ---------------- launch -----------------------------------------------------
extern "C" void kernel_launch(void* const* d_in, const int* in_sizes, int n_in,
                              void* d_out, int out_size, void* d_ws, size_t ws_size,
                              hipStream_t stream) {
  const float* x   = (const float*)d_in[0];
  const int* edges = (const int*)d_in[1];  // [2*E] int32: row0=src, row1=dst
  const float* W1  = (const float*)d_in[2];
  const float* b1  = (const float*)d_in[3];
  const float* W2  = (const float*)d_in[4];
  const float* b2  = (const float*)d_in[5];
  float* out = (float*)d_out;

  char* ws = (char*)d_ws;
  size_t off = 0;
  auto alloc = [&](size_t bytes) -> void* {
    void* p = ws + off;
    off = (off + bytes + 255) & ~(size_t)255;
    return p;
  };
  int*   rowstart = (int*)alloc((size_t)(N_NODES + 1) * 4);
  float* dinv     = (float*)alloc((size_t)N_NODES * 4);
  int*   gcursor  = (int*)alloc(256 * 4);
  int*   bstart   = (int*)alloc(256 * 4);
  int*   srcs     = (int*)alloc((size_t)N_EDGES * 4);
  float* hs1      = (float*)alloc((size_t)N_NODES * HIDDEN * 4);
  float* h1       = (float*)alloc((size_t)N_NODES * HIDDEN * 4);
  float* gs       = hs1;                 // hs1 dead after agg1; reuse for layer 2
  uint32_t* gbins = (uint32_t*)hs1;      // NB*CAP*4B = 14.5MB <= 25.6MB; dead before gemm1

  init_kernel<<<1, 256, 0, stream>>>(gcursor);
  bin_kernel<<<(N_EDGES + CHUNK - 1) / CHUNK, 256, 0, stream>>>(edges, gcursor, gbins);
  sizes_scan<<<1, 256, 0, stream>>>(gcursor, bstart, rowstart);
  node_kernel<<<NB, 512, 0, stream>>>(gbins, bstart, rowstart, srcs, dinv);
  gemm1_kernel<<<(N_NODES + 63) / 64, 256, 0, stream>>>(x, W1, dinv, hs1);
  agg_kernel<HIDDEN, true><<<(N_NODES * 64 + 255) / 256, 256, 0, stream>>>(
      hs1, rowstart, srcs, dinv, b1, h1);
  gemm2_kernel<<<(N_NODES * 64 + 255) / 256, 256, 0, stream>>>(h1, W2, dinv, gs);
  agg_kernel<N_CLASSES, false><<<(N_NODES * 64 + 255) / 256, 256, 0, stream>>>(
      gs, rowstart, srcs, dinv, b2, out);
}

// Round 5
// 724.248 us; speedup vs baseline: 1.9118x; 1.0217x over previous
//
#include <hip/hip_runtime.h>
#include <stdint.h>

#define N_NODES   100000
#define N_EDGES   3200000
#define N_FEAT    512
#define HIDDEN    64
#define N_CLASSES 40

#define BSH   9                      // bucket = dst >> 9 (512 nodes per bucket)
#define NB    196                    // ceil(100000/512)
#define CAP   18432                  // bucket region capacity; mean 16384, +16 sigma
#define CHUNK 4096                   // edges per bin_kernel workgroup

// ---------------- bf16 helpers (RNE) ----------------------------------------
__device__ __forceinline__ float bf2f(uint16_t u) {
  return __uint_as_float((uint32_t)u << 16);
}
__device__ __forceinline__ uint16_t f2bf(float f) {
  uint32_t x = __float_as_uint(f);
  return (uint16_t)((x + 0x7fffu + ((x >> 16) & 1u)) >> 16);
}

// ---------------- threefry2x32 (exact JAX semantics, key = (0,42)) ----------
__device__ __forceinline__ uint32_t rotl32(uint32_t x, uint32_t r) {
  return (x << r) | (x >> (32u - r));
}

__device__ __forceinline__ void threefry2x32(uint32_t k0, uint32_t k1,
                                             uint32_t x0, uint32_t x1,
                                             uint32_t& o0, uint32_t& o1) {
  uint32_t ks2 = k0 ^ k1 ^ 0x1BD11BDAu;
  x0 += k0; x1 += k1;
#define TF_R4(a,b,c,d) \
  x0 += x1; x1 = rotl32(x1,a); x1 ^= x0; \
  x0 += x1; x1 = rotl32(x1,b); x1 ^= x0; \
  x0 += x1; x1 = rotl32(x1,c); x1 ^= x0; \
  x0 += x1; x1 = rotl32(x1,d); x1 ^= x0;
  TF_R4(13,15,26,6)   x0 += k1;  x1 += ks2 + 1u;
  TF_R4(17,29,16,24)  x0 += ks2; x1 += k0  + 2u;
  TF_R4(13,15,26,6)   x0 += k0;  x1 += k1  + 3u;
  TF_R4(17,29,16,24)  x0 += k1;  x1 += ks2 + 4u;
  TF_R4(13,15,26,6)   x0 += ks2; x1 += k0  + 5u;
#undef TF_R4
  o0 = x0; o1 = x1;
}

// ---------------- CSR build (no per-edge global atomics anywhere) ------------
__global__ void init_kernel(int* __restrict__ gcursor) {
  int t = threadIdx.x;
  if (t < NB) gcursor[t] = t * CAP;  // fixed-capacity bucket regions
}

__global__ __launch_bounds__(256) void bin_kernel(const int* __restrict__ edges,
                                                  int* __restrict__ gcursor,
                                                  uint32_t* __restrict__ gbins) {
  __shared__ int bcnt[256];
  __shared__ int sc[256];
  __shared__ int bs[NB + 1];
  __shared__ int gbase[NB];
  __shared__ uint32_t sorted[CHUNK];

  int t = threadIdx.x;
  int base = blockIdx.x * CHUNK;
  int s[16], d[16], pos[16];
#pragma unroll
  for (int i = 0; i < 16; i++) {
    int e = base + i * 256 + t;
    if (e < N_EDGES) { s[i] = edges[e]; d[i] = edges[N_EDGES + e]; }
    else d[i] = -1;
  }
  bcnt[t] = 0;
  __syncthreads();
#pragma unroll
  for (int i = 0; i < 16; i++)
    if (d[i] >= 0) pos[i] = atomicAdd(&bcnt[d[i] >> BSH], 1);
  __syncthreads();
  sc[t] = bcnt[t];
  __syncthreads();
  for (int off = 1; off < 256; off <<= 1) {       // Hillis-Steele inclusive scan
    int v = (t >= off) ? sc[t - off] : 0;
    __syncthreads();
    sc[t] += v;
    __syncthreads();
  }
  if (t < NB) bs[t] = sc[t] - bcnt[t];            // exclusive starts
  if (t == 255) bs[NB] = sc[255];
  if (t < NB && bcnt[t] > 0) gbase[t] = atomicAdd(&gcursor[t], bcnt[t]);
  __syncthreads();
#pragma unroll
  for (int i = 0; i < 16; i++)
    if (d[i] >= 0)
      sorted[bs[d[i] >> BSH] + pos[i]] =
          ((uint32_t)s[i] << BSH) | ((uint32_t)d[i] & ((1u << BSH) - 1));
  __syncthreads();
  int total = bs[NB];
  for (int p = t; p < total; p += 256) {
    int lo = 0, hi = NB - 1;                      // bucket: bs[b] <= p < bs[b+1]
    while (lo < hi) { int mid = (lo + hi + 1) >> 1; if (bs[mid] <= p) lo = mid; else hi = mid - 1; }
    gbins[gbase[lo] + (p - bs[lo])] = sorted[p];
  }
}

__global__ void sizes_scan(const int* __restrict__ gcursor, int* __restrict__ bstart,
                           int* __restrict__ rowstart) {
  __shared__ int s[256];
  int t = threadIdx.x;
  int v = (t < NB) ? (gcursor[t] - t * CAP) : 0;
  s[t] = v; __syncthreads();
  for (int off = 1; off < 256; off <<= 1) {
    int a = (t >= off) ? s[t - off] : 0;
    __syncthreads();
    s[t] += a;
    __syncthreads();
  }
  if (t < NB) bstart[t] = s[t] - v;
  if (t == 255) bstart[NB] = s[255];              // == N_EDGES
  if (t == 0) rowstart[N_NODES] = N_EDGES;
}

__global__ __launch_bounds__(512) void node_kernel(const uint32_t* __restrict__ gbins,
                                                   const int* __restrict__ bstart,
                                                   int* __restrict__ rowstart,
                                                   int* __restrict__ srcs,
                                                   float* __restrict__ dinv) {
  __shared__ int deg[512];
  __shared__ int loc[512];
  __shared__ int cur[512];
  int b = blockIdx.x, t = threadIdx.x;
  int rbase = b * CAP;
  int obase = bstart[b];
  int sz = bstart[b + 1] - obase;
  deg[t] = 0;
  __syncthreads();
  for (int p = t; p < sz; p += 512)
    atomicAdd(&deg[gbins[rbase + p] & ((1u << BSH) - 1)], 1);
  __syncthreads();
  int v = deg[t];
  loc[t] = v;
  __syncthreads();
  for (int off = 1; off < 512; off <<= 1) {       // inclusive scan
    int a = (t >= off) ? loc[t - off] : 0;
    __syncthreads();
    loc[t] += a;
    __syncthreads();
  }
  int excl = loc[t] - v;
  cur[t] = excl;
  int node = (b << BSH) + t;
  if (node < N_NODES) {
    rowstart[node] = obase + excl;
    dinv[node] = rsqrtf((float)(v + 1));          // +1 self-loop
  }
  __syncthreads();
  for (int p = t; p < sz; p += 512) {
    uint32_t e = gbins[rbase + p];
    int pos = atomicAdd(&cur[e & ((1u << BSH) - 1)], 1);
    srcs[obase + pos] = (int)(e >> BSH);
  }
}

// ---------------- GEMM1: hs1 = bf16((x @ W1) * dinv[n])  [100000x512 @ 512x64]
#define XP 68  // padded LDS leading dim
__global__ __launch_bounds__(256) void gemm1_kernel(const float* __restrict__ x,
                                                    const float* __restrict__ W1,
                                                    const float* __restrict__ dinv,
                                                    uint16_t* __restrict__ hs1) {
  __shared__ float Xs[32 * XP];  // [k][node], transposed
  __shared__ float Ws[32 * XP];  // [k][col]
  int t = threadIdx.x;
  int node0 = blockIdx.x * 64;
  int tx = t & 15, ty = t >> 4;
  float acc[4][4];
#pragma unroll
  for (int i = 0; i < 4; i++)
#pragma unroll
    for (int j = 0; j < 4; j++) acc[i][j] = 0.f;

  for (int kc = 0; kc < N_FEAT; kc += 32) {
#pragma unroll
    for (int L = 0; L < 2; L++) {
      int f = t + L * 256;
      int kq = f & 7, row = f >> 3;
      int gr = node0 + row; if (gr > N_NODES - 1) gr = N_NODES - 1;
      const float4 v = *reinterpret_cast<const float4*>(
          &x[(size_t)gr * N_FEAT + kc + kq * 4]);
      Xs[(kq * 4 + 0) * XP + row] = v.x;
      Xs[(kq * 4 + 1) * XP + row] = v.y;
      Xs[(kq * 4 + 2) * XP + row] = v.z;
      Xs[(kq * 4 + 3) * XP + row] = v.w;
    }
#pragma unroll
    for (int L = 0; L < 2; L++) {
      int f = t + L * 256;
      int colq = f & 15, kl = f >> 4;
      const float4 v = *reinterpret_cast<const float4*>(
          &W1[(size_t)(kc + kl) * HIDDEN + colq * 4]);
      *reinterpret_cast<float4*>(&Ws[kl * XP + colq * 4]) = v;
    }
    __syncthreads();
#pragma unroll 8
    for (int kl = 0; kl < 32; kl++) {
      const float4 a = *reinterpret_cast<const float4*>(&Xs[kl * XP + ty * 4]);
      const float4 b = *reinterpret_cast<const float4*>(&Ws[kl * XP + tx * 4]);
      float ar[4] = {a.x, a.y, a.z, a.w};
      float br[4] = {b.x, b.y, b.z, b.w};
#pragma unroll
      for (int i = 0; i < 4; i++)
#pragma unroll
        for (int j = 0; j < 4; j++) acc[i][j] += ar[i] * br[j];
    }
    __syncthreads();
  }
#pragma unroll
  for (int i = 0; i < 4; i++) {
    int node = node0 + ty * 4 + i;
    if (node < N_NODES) {
      float dv = dinv[node];
      ushort4 o;
      o.x = f2bf(acc[i][0] * dv); o.y = f2bf(acc[i][1] * dv);
      o.z = f2bf(acc[i][2] * dv); o.w = f2bf(acc[i][3] * dv);
      *reinterpret_cast<ushort4*>(&hs1[(size_t)node * HIDDEN + tx * 4]) = o;
    }
  }
}

// ---------------- GEMM2: gs = bf16((h1 @ W2) * dinv[n])  [100000x64 @ 64x40] -
__global__ __launch_bounds__(256) void gemm2_kernel(const float* __restrict__ h1,
                                                    const float* __restrict__ W2,
                                                    const float* __restrict__ dinv,
                                                    uint16_t* __restrict__ gs) {
  __shared__ float w2s[HIDDEN * N_CLASSES + 64];
  int t = threadIdx.x;
  for (int i = t; i < HIDDEN * N_CLASSES; i += 256) w2s[i] = W2[i];
  __syncthreads();
  int wid = (blockIdx.x * 256 + t) >> 6;
  int lane = t & 63;
  if (wid >= N_NODES) return;
  float hv = h1[(size_t)wid * HIDDEN + lane];
  float acc = 0.f;
#pragma unroll 8
  for (int j = 0; j < HIDDEN; j++) {
    float hj = __shfl(hv, j);
    acc += hj * w2s[j * N_CLASSES + lane];
  }
  if (lane < N_CLASSES) gs[(size_t)wid * N_CLASSES + lane] = f2bf(acc * dinv[wid]);
}

// -------- Pull aggregation (bf16 gather): out[d]=dinv[d]*(hs[d]+sum hs[src])+b
template <int F, bool RELU_DROP>
__global__ __launch_bounds__(256) void agg_kernel(const uint16_t* __restrict__ hs,
                                                  const int* __restrict__ rowstart,
                                                  const int* __restrict__ srcs,
                                                  const float* __restrict__ dinv,
                                                  const float* __restrict__ bias,
                                                  float* __restrict__ outp) {
  int wid = (blockIdx.x * 256 + threadIdx.x) >> 6;  // one wave per dst node
  int lane = threadIdx.x & 63;
  if (wid >= N_NODES) return;
  int beg = rowstart[wid], end = rowstart[wid + 1];
  float acc = 0.f;
  if (lane < F) acc = bf2f(hs[(size_t)wid * F + lane]);  // self-loop term
  int e = beg;
  for (; e + 4 <= end; e += 4) {                    // 4 gathers in flight
    int s0 = srcs[e], s1 = srcs[e + 1], s2 = srcs[e + 2], s3 = srcs[e + 3];
    if (lane < F) {
      float a0 = bf2f(hs[(size_t)s0 * F + lane]);
      float a1 = bf2f(hs[(size_t)s1 * F + lane]);
      float a2 = bf2f(hs[(size_t)s2 * F + lane]);
      float a3 = bf2f(hs[(size_t)s3 * F + lane]);
      acc += (a0 + a1) + (a2 + a3);
    }
  }
  for (; e < end; ++e) {
    int s = srcs[e];
    if (lane < F) acc += bf2f(hs[(size_t)s * F + lane]);
  }
  if (lane < F) {
    float v = acc * dinv[wid] + bias[lane];
    if (RELU_DROP) {
      v = fmaxf(v, 0.f);
      // JAX dropout, jax_threefry_partitionable=True:
      // bits(i) = o0^o1 of threefry2x32(key=(0,42), (0,i)); drop iff bit31 set.
      uint32_t i = (uint32_t)wid * 64u + (uint32_t)lane;
      uint32_t o0, o1;
      threefry2x32(0u, 42u, 0u, i, o0, o1);
      uint32_t bits = o0 ^ o1;
      v = (bits & 0x80000000u) ? 0.f : v * 2.f;
    }
    outp[(size_t)wid * F + lane] = v;
  }
}

// ---------------- launch -----------------------------------------------------
extern "C" void kernel_launch(void* const* d_in, const int* in_sizes, int n_in,
                              void* d_out, int out_size, void* d_ws, size_t ws_size,
                              hipStream_t stream) {
  const float* x   = (const float*)d_in[0];
  const int* edges = (const int*)d_in[1];  // [2*E] int32: row0=src, row1=dst
  const float* W1  = (const float*)d_in[2];
  const float* b1  = (const float*)d_in[3];
  const float* W2  = (const float*)d_in[4];
  const float* b2  = (const float*)d_in[5];
  float* out = (float*)d_out;

  char* ws = (char*)d_ws;
  size_t off = 0;
  auto alloc = [&](size_t bytes) -> void* {
    void* p = ws + off;
    off = (off + bytes + 255) & ~(size_t)255;
    return p;
  };
  int*      rowstart = (int*)alloc((size_t)(N_NODES + 1) * 4);
  float*    dinv     = (float*)alloc((size_t)N_NODES * 4);
  int*      gcursor  = (int*)alloc(256 * 4);
  int*      bstart   = (int*)alloc(256 * 4);
  int*      srcs     = (int*)alloc((size_t)N_EDGES * 4);
  uint32_t* gbins    = (uint32_t*)alloc((size_t)NB * CAP * 4);
  uint16_t* hs1      = (uint16_t*)alloc((size_t)N_NODES * HIDDEN * 2);
  float*    h1       = (float*)alloc((size_t)N_NODES * HIDDEN * 4);
  uint16_t* gs       = (uint16_t*)alloc((size_t)N_NODES * N_CLASSES * 2);

  init_kernel<<<1, 256, 0, stream>>>(gcursor);
  bin_kernel<<<(N_EDGES + CHUNK - 1) / CHUNK, 256, 0, stream>>>(edges, gcursor, gbins);
  sizes_scan<<<1, 256, 0, stream>>>(gcursor, bstart, rowstart);
  node_kernel<<<NB, 512, 0, stream>>>(gbins, bstart, rowstart, srcs, dinv);
  gemm1_kernel<<<(N_NODES + 63) / 64, 256, 0, stream>>>(x, W1, dinv, hs1);
  agg_kernel<HIDDEN, true><<<(N_NODES * 64 + 255) / 256, 256, 0, stream>>>(
      hs1, rowstart, srcs, dinv, b1, h1);
  gemm2_kernel<<<(N_NODES * 64 + 255) / 256, 256, 0, stream>>>(h1, W2, dinv, gs);
  agg_kernel<N_CLASSES, false><<<(N_NODES * 64 + 255) / 256, 256, 0, stream>>>(
      gs, rowstart, srcs, dinv, b2, out);
}